// Round 12
// baseline (7639.142 us; speedup 1.0000x reference)
//
#include <hip/hip_runtime.h>

// drosophRNN v12: TWO batches per 512-thread block (grid=32). Rationale: R7-R11
// showed per-step time pinned at ~1870 cy regardless of VALU/LDS/barrier cuts
// -> latency-bound (post-barrier LDS latency + dep chains + barrier skew).
// A second independent batch in the same block fills those bubbles.
//  - threads 0..255 batch 2b, 256..511 batch 2b+1 (bb wave-uniform).
//  - per batch: matvec = 25 groups x 8 lanes, K=4 outputs, 40 permuted
//    positions/lane (v11 permuted layout; b128 state ops); aux = 56 lanes:
//    w1 T0 + stream, w2 rank-3 D7 with 48-lane DPP reduction.
//  - 512-thr block => VGPR cap 256 (v10's spill was the 1024-thr 64-cap).
//  - lgkm-only barriers (v9).

#define SSTEPS 5000
#define PI_D 3.14159265358979323846

typedef float f2 __attribute__((ext_vector_type(2)));

__device__ __forceinline__ f2 pk_fma(f2 a, f2 b, f2 c) {
  f2 d;
  asm("v_pk_fma_f32 %0, %1, %2, %3" : "=v"(d) : "v"(a), "v"(b), "v"(c));
  return d;
}

template<int CTRL, int RM, bool BC>
__device__ __forceinline__ float dpp_mov_f(float x) {
  return __int_as_float(__builtin_amdgcn_update_dpp(0, __float_as_int(x), CTRL, RM, 0xF, BC));
}
__device__ __forceinline__ float scan16(float x) {   // lane15(+16k) = 16-row sum
  x += dpp_mov_f<0x111,0xF,true>(x);
  x += dpp_mov_f<0x112,0xF,true>(x);
  x += dpp_mov_f<0x114,0xF,true>(x);
  x += dpp_mov_f<0x118,0xF,true>(x);
  return x;
}
__device__ __forceinline__ float scan8(float x) {    // lane 8k+7 = 8-group sum
  x += dpp_mov_f<0x111,0xF,true>(x);
  x += dpp_mov_f<0x112,0xF,true>(x);
  x += dpp_mov_f<0x114,0xF,true>(x);
  return x;
}
// sum over lanes 0..47 (rows 0-2); broadcast to all lanes via readlane 47.
__device__ __forceinline__ float wave_sum48(float x) {
  x = scan16(x);
  x += dpp_mov_f<0x142,0x2,false>(x);   // row_bcast15 -> row 1 (lane31 += lane15)
  x += dpp_mov_f<0x143,0x4,false>(x);   // row_bcast31 -> row 2 (lane47 += lane31)
  return __int_as_float(__builtin_amdgcn_readlane(__float_as_int(x), 47));
}
// lgkm-only barrier (v9-verified): global stores stay in flight.
__device__ __forceinline__ void bar_lgkm() {
  asm volatile("s_waitcnt lgkmcnt(0)\n\ts_barrier" ::: "memory");
}

// permuted layout (v11-validated): HD pos 4g+k = neuron g+25k;
// AV pos 100+4a+m = {AVp[a],AVm[a],AVp[a+25],AVm[a+25]}; D7 natural.
__device__ __forceinline__ int neuron_of_pos(int pos) {
  if (pos < 100) return (pos >> 2) + 25 * (pos & 3);
  if (pos < 200) {
    int r = pos - 100, a = r >> 2, m = r & 3;
    return 100 + a + (m == 0 ? 0 : (m == 1 ? 50 : (m == 2 ? 25 : 75)));
  }
  return pos;
}
__device__ __forceinline__ int pos_of_neuron(int n) {
  if (n < 100) return 4 * (n % 25) + n / 25;
  if (n < 200) {
    int uu = n - 100, half = (uu >= 50) ? 1 : 0, w = uu - 50 * half;
    return 100 + 4 * (w % 25) + 2 * (w / 25) + half;
  }
  return n;
}

__global__
__attribute__((amdgpu_flat_work_group_size(512,512)))
__attribute__((amdgpu_waves_per_eu(2)))
void drosoph_rnn_kernel(
    const float* __restrict__ xin,      // (64,5000,2)
    const float* __restrict__ r0,       // (1,64,300)
    const float* __restrict__ W_HD_HD,  // (100,100)
    const float* __restrict__ W_HD_AVp, // (100,50)
    const float* __restrict__ W_HD_AVm, // (100,50)
    const float* __restrict__ W_AVp_HD, // (50,100)  == W_AVm_HD
    const float* __restrict__ W_AVm_HD, // (50,100)
    const float* __restrict__ W_D7_HD,  // factorized analytically
    const float* __restrict__ W_D7_D7,  // rank-1 (0.002)
    const float* __restrict__ W_HD_D7,  // (100,100)
    float* __restrict__ out)            // 64*5000*300 + 64*300
{
  const int bid  = blockIdx.x;
  const int t    = threadIdx.x;
  const int bb   = t >> 8;             // batch half (wave-uniform: waves 0-3 / 4-7)
  const int L    = t & 255;            // lane within batch block
  const int b    = 2*bid + bb;

  __shared__ __align__(16) float su[2][2][328];   // [batch][parity][pos]
  __shared__ float avb[2][SSTEPS];
  __shared__ float d7r[2][104];

  const bool aux = (L < 56);
  const bool mv  = (L >= 56);
  const int  mg  = (L - 56) >> 3;      // matvec group 0..24
  const int  mq  = (L - 56) & 7;       // slice [40mq, 40mq+40)

  const float kAV = 0.70710678118654752f;

  // ---- matvec weights: K=4 outputs (mg+25k), 40 permuted positions/lane ----
  f2 w1p[4][20];
  if (mv) {
    #pragma unroll
    for (int k = 0; k < 4; ++k) {
      const int o = mg + 25*k;
      #pragma unroll
      for (int q = 0; q < 40; ++q) {
        const int pos = 40*mq + q;
        const int n   = neuron_of_pos(pos);
        float w = 0.0f;
        if      (n < 100) w = 10.5f * W_HD_HD [o*100 + n];
        else if (n < 150) w = kAV   * W_HD_AVp[o*50 + (n-100)];
        else if (n < 200) w = kAV   * W_HD_AVm[o*50 + (n-150)];
        else if (n < 300) w = 0.5f  * W_HD_D7 [o*100 + (n-200)];
        w1p[k][q >> 1][q & 1] = w;
      }
    }
  }

  // ---- AV weights: K=2 (outputs mg, mg+25), chunk-interleaved (v11) ----
  f2 wavK[2][8];
  if (mv) {
    #pragma unroll
    for (int m = 0; m < 2; ++m) {
      const int a2 = mg + 25*m;
      #pragma unroll
      for (int u = 0; u < 4; ++u) {
        #pragma unroll
        for (int mm = 0; mm < 4; ++mm) {
          const int pos = 4*(mq + 8*u) + mm;
          float w = 0.0f;
          if (pos < 100) w = W_AVp_HD[a2*100 + neuron_of_pos(pos)];
          wavK[m][2*u + (mm >> 1)][mm & 1] = w;
        }
      }
    }
  }

  // ---- aux constants: D7 partial-trig (cols L, L+48, L+96) + output trig ----
  int posA = 0, posB = 0, posC = 0;
  float cw0=0,cw1=0,cw2=0,sw0=0,sw1=0,sw2=0;
  float cdA=0,sdA=0,cdB=0,sdB=0;
  if (aux) {
    if (L < 48) {
      posA = pos_of_neuron(L);
      posB = pos_of_neuron(L+48);
      posC = (L < 4) ? pos_of_neuron(L+96) : posA;
      double p0 = -PI_D + L     *(2.0*PI_D/100.0);
      double p1 = -PI_D + (L+48)*(2.0*PI_D/100.0);
      cw0=(float)cos(p0); sw0=(float)sin(p0);
      cw1=(float)cos(p1); sw1=(float)sin(p1);
      if (L < 4) {
        double p2 = -PI_D + (L+96)*(2.0*PI_D/100.0);
        cw2=(float)cos(p2); sw2=(float)sin(p2);
      }
    }
    if (L < 50) {
      double pa = -PI_D + (2*L)  *(2.0*PI_D/100.0);
      double pb = -PI_D + (2*L+1)*(2.0*PI_D/100.0);
      cdA=(float)cos(pa); sdA=(float)sin(pa);
      cdB=(float)cos(pb); sdB=(float)sin(pb);
    }
  }

  // ---- init LDS ----
  for (int i = t; i < 2*2*328;  i += 512) (&su[0][0][0])[i] = 0.f;
  for (int i = t; i < 2*104;    i += 512) (&d7r[0][0])[i]   = 0.f;
  for (int i = t; i < 2*SSTEPS; i += 512) {
    int b2 = i / SSTEPS, s2 = i - b2*SSTEPS;
    const float2* x2 = (const float2*)xin + (size_t)(2*bid + b2)*SSTEPS;
    avb[b2][s2] = x2[s2].y;
  }
  for (int i = t; i < 600; i += 512) {
    int b2 = i / 300, n = i - b2*300;
    float v = r0[(size_t)(2*bid + b2)*300 + n];
    if (n >= 200) v = fmaxf(v, 0.f);
    su[b2][0][pos_of_neuron(n)] = v;
  }
  __syncthreads();   // prologue only

  float*       outb = out + (size_t)b * ((size_t)SSTEPS*300);
  const float* avbb = avb[bb];
  float*       d7rb = d7r[bb];
  int p = 0;

  #pragma unroll 1
  for (int s = 0; s < SSTEPS; ++s) {
    const float* sucb = su[bb][p];
    float*       sunb = su[bb][p^1];
    float T0loc = 0.f;

    // =============== window 1: matvec (K=4) / T0 + stream ===============
    if (mv) {
      const float4* vp  = (const float4*)(sucb + 40*mq);
      const float4  hd4 = *(const float4*)(sucb + 4*mg);  // {hd[g],hd[g+25],hd[g+50],hd[g+75]}
      f2 cX0={0,0},cX1={0,0},cX2={0,0},cX3={0,0};
      f2 cY0={0,0},cY1={0,0},cY2={0,0},cY3={0,0};
      #pragma unroll
      for (int r = 0; r < 10; ++r) {
        float4 V = vp[r];
        f2 vlo = f2{V.x, V.y}, vhi = f2{V.z, V.w};
        cX0 = pk_fma(w1p[0][2*r],   vlo, cX0);
        cY0 = pk_fma(w1p[0][2*r+1], vhi, cY0);
        cX1 = pk_fma(w1p[1][2*r],   vlo, cX1);
        cY1 = pk_fma(w1p[1][2*r+1], vhi, cY1);
        cX2 = pk_fma(w1p[2][2*r],   vlo, cX2);
        cY2 = pk_fma(w1p[2][2*r+1], vhi, cY2);
        cX3 = pk_fma(w1p[3][2*r],   vlo, cX3);
        cY3 = pk_fma(w1p[3][2*r+1], vhi, cY3);
      }
      float e0 = (cX0[0]+cX0[1]) + (cY0[0]+cY0[1]);
      float e1 = (cX1[0]+cX1[1]) + (cY1[0]+cY1[1]);
      float e2 = (cX2[0]+cX2[1]) + (cY2[0]+cY2[1]);
      float e3 = (cX3[0]+cX3[1]) + (cY3[0]+cY3[1]);
      // slices mq>=5 are exactly positions >=200 (D7 cols): multiply by r_HD
      if (mq >= 5) { e0 *= hd4.x; e1 *= hd4.y; e2 *= hd4.z; e3 *= hd4.w; }
      e0 = scan8(e0); e1 = scan8(e1); e2 = scan8(e2); e3 = scan8(e3);
      if (mq == 7) {
        float h0 = fmaf(0.001f, fmaf(-10.25f, hd4.x, e0), hd4.x);
        float h1 = fmaf(0.001f, fmaf(-10.25f, hd4.y, e1), hd4.y);
        float h2 = fmaf(0.001f, fmaf(-10.25f, hd4.z, e2), hd4.z);
        float h3 = fmaf(0.001f, fmaf(-10.25f, hd4.w, e3), hd4.w);
        *(float4*)(sunb + 4*mg) = make_float4(h0, h1, h2, h3);
      }
    } else {
      // aux: T0 = sum relu(D7(s-1)) over cols {L, L+48, L+96}
      float x = 0.f;
      if (L < 48) {
        x = sucb[200+L] + sucb[248+L];
        if (L < 4) x += sucb[296+L];
      }
      T0loc = wave_sum48(x);
      if (s > 0) {   // stream output row s-1 (un-permute)
        float* od = outb + (size_t)(s-1)*300;
        #pragma unroll
        for (int u = 0; u < 6; ++u) {
          int idx = L + 56*u;
          if (idx < 300) {
            float v;
            if (idx < 100) {
              v = sucb[4*(idx % 25) + idx/25];
            } else if (idx < 200) {
              const int uu = idx - 100, half = (uu >= 50) ? 1 : 0;
              const int w_ = uu - 50*half;
              v = sucb[100 + 4*(w_ % 25) + 2*(w_/25) + half];
            } else {
              v = d7rb[idx - 200];
            }
            od[idx] = v;
          }
        }
      }
    }
    bar_lgkm();

    // =============== window 2: AV (K=2) / D7 ===============
    if (mv) {
      const float4* hp = (const float4*)sunb;   // permuted hdnew; pos>=100 x 0-weight
      float4 H0 = hp[mq], H1 = hp[mq+8], H2 = hp[mq+16], H3 = hp[mq+24];
      f2 hh2[8];
      hh2[0] = f2{H0.x, H0.y}; hh2[1] = f2{H0.z, H0.w};
      hh2[2] = f2{H1.x, H1.y}; hh2[3] = f2{H1.z, H1.w};
      hh2[4] = f2{H2.x, H2.y}; hh2[5] = f2{H2.z, H2.w};
      hh2[6] = f2{H3.x, H3.y}; hh2[7] = f2{H3.z, H3.w};
      f2 d0 = f2{0.f,0.f}, d1 = f2{0.f,0.f};
      #pragma unroll
      for (int u = 0; u < 8; ++u) {
        d0 = pk_fma(wavK[0][u], hh2[u], d0);
        d1 = pk_fma(wavK[1][u], hh2[u], d1);
      }
      const float s0v = scan8(d0[0] + d0[1]);
      const float s1v = scan8(d1[0] + d1[1]);
      if (mq == 7) {
        const float gp  = avbb[s] * 1000.0f;    // av/DT, AV_OFFSET=0
        const float4 av4 = *(const float4*)(sucb + 100 + 4*mg);  // {p0,m0,p1,m1}
        const float np0 = fmaf(0.1f, fmaf(gp,  s0v, -av4.x), av4.x);  // DT/TAU_AV=0.1
        const float nm0 = fmaf(0.1f, fmaf(-gp, s0v, -av4.y), av4.y);
        const float np1 = fmaf(0.1f, fmaf(gp,  s1v, -av4.z), av4.z);
        const float nm1 = fmaf(0.1f, fmaf(-gp, s1v, -av4.w), av4.w);
        *(float4*)(sunb + 100 + 4*mg) = make_float4(np0, nm0, np1, nm1);
      }
    } else {
      // D7 (memoryless, rank-3): partials over relu(hdnew) cols {L, L+48, L+96}
      float y0 = 0.f, y1 = 0.f, y2 = 0.f;
      if (L < 48) {
        y0 = fmaxf(sunb[posA], 0.f);
        y1 = fmaxf(sunb[posB], 0.f);
        y2 = (L < 4) ? fmaxf(sunb[posC], 0.f) : 0.f;
      }
      float pS0 = (y0 + y1) + y2;
      float pC  = cw0*y0 + cw1*y1 + cw2*y2;
      float pS  = sw0*y0 + sw1*y1 + sw2*y2;
      float S0 = wave_sum48(pS0);
      float C  = wave_sum48(pC);
      float S  = wave_sum48(pS);
      float base = fmaf(0.002f, T0loc, 0.01f * S0);
      if (L < 50) {
        float da = base - 0.01f * fmaf(cdA, C, sdA * S);   // col 2L
        float db = base - 0.01f * fmaf(cdB, C, sdB * S);   // col 2L+1
        *(float2*)(sunb + 200 + 2*L) = make_float2(fmaxf(da, 0.f), fmaxf(db, 0.f));
        *(float2*)(d7rb + 2*L)       = make_float2(da, db);
      }
    }
    bar_lgkm();
    p ^= 1;
  }

  // =============== epilogue: row 4999 + final carry (un-permute) ===============
  #pragma unroll
  for (int u = 0; u < 2; ++u) {
    int idx = L + 256*u;
    if (idx < 300) {
      float v;
      if (idx < 100) {
        v = su[bb][p][4*(idx % 25) + idx/25];
      } else if (idx < 200) {
        const int uu = idx - 100, half = (uu >= 50) ? 1 : 0;
        const int w_ = uu - 50*half;
        v = su[bb][p][100 + 4*(w_ % 25) + 2*(w_/25) + half];
      } else {
        v = d7rb[idx - 200];
      }
      outb[(size_t)(SSTEPS-1)*300 + idx] = v;
      out[(size_t)64*SSTEPS*300 + (size_t)b*300 + idx] = v;
    }
  }
}

extern "C" void kernel_launch(void* const* d_in, const int* in_sizes, int n_in,
                              void* d_out, int out_size, void* d_ws, size_t ws_size,
                              hipStream_t stream) {
  drosoph_rnn_kernel<<<32, 512, 0, stream>>>(
      (const float*)d_in[0],  // inputs
      (const float*)d_in[1],  // r0
      (const float*)d_in[2],  // W_HD_HD
      (const float*)d_in[3],  // W_HD_AVplus
      (const float*)d_in[4],  // W_HD_AVminus
      (const float*)d_in[5],  // W_AVplus_HD
      (const float*)d_in[6],  // W_AVminus_HD
      (const float*)d_in[7],  // W_Del7_HD
      (const float*)d_in[8],  // W_Del7_Del7
      (const float*)d_in[9],  // W_HD_Del7
      (float*)d_out);
}

// Round 13
// 4651.658 us; speedup vs baseline: 1.6422x; 1.6422x over previous
//
#include <hip/hip_runtime.h>

// drosophRNN v13: v9 chassis (fastest, 3886us) with ONE structural change:
// the D7 rank-3 reduction moves from window 2 (serial triple wave_sum on the
// D7 wave) into window 1's producers:
//   - producers (r1==15) compute 3 partials from their in-register h0,h1
//     (pair (g,g+50): phase p+pi -> cos/sin negate; 3 muls)
//   - per-wave combine via 2 row_bcast DPP adds (VALU pipe, NOT the v3 xor
//     shuffles which are LDS-pipe) -> lane 63 writes 3 floats to pbuf
//   - window 2 D7 = 1 b32 read + 1 packed scan16 + 3 readlanes + formula
// Everything else identical to v9. 960 threads (wave 13 = T0+D7, 14 = stream).

#define SSTEPS 5000
#define PI_D 3.14159265358979323846

typedef float f2 __attribute__((ext_vector_type(2)));

__device__ __forceinline__ f2 pk_fma(f2 a, f2 b, f2 c) {
  f2 d;
  asm("v_pk_fma_f32 %0, %1, %2, %3" : "=v"(d) : "v"(a), "v"(b), "v"(c));
  return d;
}

template<int CTRL, int RM, bool BC>
__device__ __forceinline__ float dpp_mov_f(float x) {
  return __int_as_float(__builtin_amdgcn_update_dpp(0, __float_as_int(x), CTRL, RM, 0xF, BC));
}
__device__ __forceinline__ float scan16(float x) {   // lane15(+16k) = 16-row sum
  x += dpp_mov_f<0x111,0xF,true>(x);
  x += dpp_mov_f<0x112,0xF,true>(x);
  x += dpp_mov_f<0x114,0xF,true>(x);
  x += dpp_mov_f<0x118,0xF,true>(x);
  return x;
}
__device__ __forceinline__ float scan8(float x) {    // lane7(+8k) = 8-group sum
  x += dpp_mov_f<0x111,0xF,true>(x);
  x += dpp_mov_f<0x112,0xF,true>(x);
  x += dpp_mov_f<0x114,0xF,true>(x);
  return x;
}
__device__ __forceinline__ float wave_sum(float x) { // all-VALU (DPP) + readlane
  x = scan16(x);
  x += dpp_mov_f<0x142,0xA,false>(x);  // row_bcast15
  x += dpp_mov_f<0x143,0xC,false>(x);  // row_bcast31
  return __int_as_float(__builtin_amdgcn_readlane(__float_as_int(x), 63));
}
__device__ __forceinline__ float bcast_lane(float x, int l) {
  return __int_as_float(__builtin_amdgcn_readlane(__float_as_int(x), l));
}
// lgkm-only barrier (v9-verified): global stores stay in flight.
__device__ __forceinline__ void bar_lgkm() {
  asm volatile("s_waitcnt lgkmcnt(0)\n\ts_barrier" ::: "memory");
}

__global__ __launch_bounds__(960, 4) void drosoph_rnn_kernel(
    const float* __restrict__ xin,      // (64,5000,2)
    const float* __restrict__ r0,       // (1,64,300)
    const float* __restrict__ W_HD_HD,  // (100,100)
    const float* __restrict__ W_HD_AVp, // (100,50)
    const float* __restrict__ W_HD_AVm, // (100,50)
    const float* __restrict__ W_AVp_HD, // (50,100)
    const float* __restrict__ W_AVm_HD, // (50,100)  (== W_AVp_HD)
    const float* __restrict__ W_D7_HD,  // factorized analytically
    const float* __restrict__ W_D7_D7,  // rank-1 (0.002)
    const float* __restrict__ W_HD_D7,  // (100,100)
    float* __restrict__ out)            // 64*5000*300 + 64*300
{
  const int b    = blockIdx.x;
  const int t    = threadIdx.x;
  const int lane = t & 63;
  const int wid  = t >> 6;

  // state per parity: [0..99] HD, [100..149] AVp, [150..199] AVm,
  // [200..299] relu(D7), [300..327] zero pad
  __shared__ __align__(16) float su[2][328];
  __shared__ float avb[SSTEPS];   // x[:,1] for this batch
  __shared__ float d7r[104];      // raw D7 (current step)
  __shared__ float pbuf[64];      // rows: S0-partials[13] | C-partials | S-partials | 0

  // ---- roles ----
  const bool p1  = (t < 800);            // phase1: 50 pairs x 16 lanes
  const int  g   = t >> 4;               // pair -> outputs (g, g+50)
  const int  r1  = t & 15;               // j-slice [20*r1, 20*r1+20)
  const bool pav = (t < 400);            // AV: 50 groups x 8 lanes (one shared dot)
  const int  a   = t >> 3;
  const int  qa  = t & 7;
  const bool d7w = (wid == 13);          // w1: T0; w2: D7 finalize
  const bool pst = (wid == 14);          // w1: output streaming

  // ---- phase-1 weights (scales folded), packed into float2 pairs ----
  f2 w1p[2][10];
  if (p1) {
    #pragma unroll
    for (int k = 0; k < 2; ++k) {
      const int o = g + 50*k;
      #pragma unroll
      for (int q = 0; q < 20; ++q) {
        const int j = 20*r1 + q;
        float w;
        if      (j < 100) w = 10.5f                * W_HD_HD [o*100 + j];
        else if (j < 150) w = 0.70710678118654752f * W_HD_AVp[o*50 + (j-100)];
        else if (j < 200) w = 0.70710678118654752f * W_HD_AVm[o*50 + (j-150)];
        else if (j < 300) w = 0.5f                 * W_HD_D7 [o*100 + (j-200)];
        else w = 0.0f;
        w1p[k][q >> 1][q & 1] = w;
      }
    }
  }

  // ---- AV weights, chunk-interleaved (qa, qa+8, qa+16, qa+24), packed ----
  f2 wavp[8];
  if (pav) {
    #pragma unroll
    for (int u = 0; u < 4; ++u) {
      const int j0 = 4*(qa + 8*u);
      #pragma unroll
      for (int m = 0; m < 4; ++m) {
        const int j = j0 + m;
        float w = (j < 100) ? W_AVp_HD[a*100 + j] : 0.0f;
        wavp[2*u + (m >> 1)][m & 1] = w;
      }
    }
  }

  // ---- trig constants ----
  float cg = 0.f, sg = 0.f;          // producers: phase of output g
  if (p1 && r1 == 15) {
    double pg = -PI_D + g * (2.0*PI_D/100.0);
    cg = (float)cos(pg); sg = (float)sin(pg);
  }
  float cdA=0.f, sdA=0.f, cdB=0.f, sdB=0.f;   // D7 wave: cols 2*lane, 2*lane+1
  if (d7w) {
    double pa = -PI_D + (2*lane)  *(2.0*PI_D/100.0);
    double pb = -PI_D + (2*lane+1)*(2.0*PI_D/100.0);
    cdA = (float)cos(pa); sdA = (float)sin(pa);
    cdB = (float)cos(pb); sdB = (float)sin(pb);
  }

  // ---- init LDS ----
  if (t < 328) { su[0][t] = 0.f; su[1][t] = 0.f; }
  if (t < 104) d7r[t] = 0.f;
  if (t < 64)  pbuf[t] = 0.f;       // cols 13-15 + row 3 stay 0 forever
  {
    const float2* x2 = (const float2*)xin + (size_t)b * SSTEPS;
    for (int i = t; i < SSTEPS; i += 960) avb[i] = x2[i].y;
  }
  if (t < 300) {
    float v = r0[b*300 + t];
    su[0][t] = (t < 200) ? v : fmaxf(v, 0.f);
  }
  __syncthreads();   // prologue only

  float* outb = out + (size_t)b * ((size_t)SSTEPS * 300);
  int p = 0;

  #pragma unroll 1
  for (int s = 0; s < SSTEPS; ++s) {
    const float* suc = su[p];
    float*       sun = su[p^1];
    float T0loc = 0.f;
    float q0 = 0.f, q1 = 0.f, q2 = 0.f;   // D7 partials (producers only)

    // ---------- window 1: HD matvec / T0 / stream ----------
    if (p1) {
      f2 vv2[10];
      {
        const float4* vp = (const float4*)(suc + 20*r1);
        float4 V0=vp[0], V1=vp[1], V2=vp[2], V3=vp[3], V4=vp[4];
        vv2[0] = f2{V0.x, V0.y}; vv2[1] = f2{V0.z, V0.w};
        vv2[2] = f2{V1.x, V1.y}; vv2[3] = f2{V1.z, V1.w};
        vv2[4] = f2{V2.x, V2.y}; vv2[5] = f2{V2.z, V2.w};
        vv2[6] = f2{V3.x, V3.y}; vv2[7] = f2{V3.z, V3.w};
        vv2[8] = f2{V4.x, V4.y}; vv2[9] = f2{V4.z, V4.w};
      }
      float hd0 = suc[g], hd1 = suc[g+50];
      f2 a0 = f2{0.f,0.f}, b0 = f2{0.f,0.f};
      f2 a1 = f2{0.f,0.f}, b1 = f2{0.f,0.f};
      #pragma unroll
      for (int q = 0; q < 10; q += 2) {
        a0 = pk_fma(w1p[0][q],   vv2[q],   a0);
        b0 = pk_fma(w1p[0][q+1], vv2[q+1], b0);
        a1 = pk_fma(w1p[1][q],   vv2[q],   a1);
        b1 = pk_fma(w1p[1][q+1], vv2[q+1], b1);
      }
      float e0 = (a0[0] + a0[1]) + (b0[0] + b0[1]);
      float e1 = (a1[0] + a1[1]) + (b1[0] + b1[1]);
      if (r1 >= 10) { e0 *= hd0; e1 *= hd1; }   // D7 cols multiply r_HD
      e0 = scan16(e0);
      e1 = scan16(e1);
      if (r1 == 15) {
        float h0 = fmaf(0.001f, fmaf(-10.25f, hd0, e0), hd0);
        float h1 = fmaf(0.001f, fmaf(-10.25f, hd1, e1), hd1);
        sun[g]    = h0;
        sun[g+50] = h1;
        float rh0 = fmaxf(h0, 0.f), rh1 = fmaxf(h1, 0.f);
        q0 = rh0 + rh1;                 // p_{g+50} = p_g + pi -> cos/sin negate
        float dr = rh0 - rh1;
        q1 = cg * dr;
        q2 = sg * dr;
      }
    } else if (d7w) {
      // T0 = sum relu(D7(s-1)) — step-old data
      float x = 0.f;
      if (lane < 50) { float2 z = *(const float2*)(suc + 200 + 2*lane); x = z.x + z.y; }
      T0loc = wave_sum(x);
    } else if (pst) {
      if (s > 0) {     // stream output row s-1 while others compute
        float* od = outb + (size_t)(s-1) * 300;
        #pragma unroll
        for (int u = 0; u < 5; ++u) {
          int idx = lane + 64*u;
          if (idx < 300) od[idx] = (idx < 200) ? suc[idx] : d7r[idx-200];
        }
      }
    }
    // cross-producer combine (waves 0..12; VALU DPP row_bcast, NOT xor-shuffle):
    // producers sit at lanes 15,31,47,63 with q*, all other lanes 0
    if (t < 832) {
      q0 += dpp_mov_f<0x142,0xA,false>(q0);   // lane31+=lane15, lane63+=lane47
      q1 += dpp_mov_f<0x142,0xA,false>(q1);
      q2 += dpp_mov_f<0x142,0xA,false>(q2);
      q0 += dpp_mov_f<0x143,0xC,false>(q0);   // lane63+=lane31
      q1 += dpp_mov_f<0x143,0xC,false>(q1);
      q2 += dpp_mov_f<0x143,0xC,false>(q2);
      if (lane == 63) {
        pbuf[wid]      = q0;
        pbuf[16 + wid] = q1;
        pbuf[32 + wid] = q2;
      }
    }
    bar_lgkm();

    // ---------- window 2: AVp/AVm (threads 0..399) / D7 finalize (wave 13) ----------
    if (pav) {
      const float4* hp = (const float4*)sun;    // hdnew[0..99] + zero pad
      float4 H0 = hp[qa], H1 = hp[qa+8], H2 = hp[qa+16], H3 = hp[qa+24];
      f2 hh2[8];
      hh2[0] = f2{H0.x, H0.y}; hh2[1] = f2{H0.z, H0.w};
      hh2[2] = f2{H1.x, H1.y}; hh2[3] = f2{H1.z, H1.w};
      hh2[4] = f2{H2.x, H2.y}; hh2[5] = f2{H2.z, H2.w};
      hh2[6] = f2{H3.x, H3.y}; hh2[7] = f2{H3.z, H3.w};
      f2 d0 = f2{0.f,0.f}, d1 = f2{0.f,0.f};
      #pragma unroll
      for (int u = 0; u < 8; u += 2) {
        d0 = pk_fma(wavp[u],   hh2[u],   d0);
        d1 = pk_fma(wavp[u+1], hh2[u+1], d1);
      }
      float d = scan8((d0[0] + d0[1]) + (d1[0] + d1[1]));
      if (qa == 7) {
        float av   = avb[s];
        float gp   = av * 1000.0f;       // av/DT, AV_OFFSET=0
        float oldp = suc[100+a], oldm = suc[150+a];
        float np_  = fmaf(0.1f, fmaf(gp,  d, -oldp), oldp);   // DT/TAU_AV = 0.1
        float nm_  = fmaf(0.1f, fmaf(-gp, d, -oldm), oldm);
        sun[100+a] = np_;
        sun[150+a] = nm_;
      }
    } else if (d7w) {
      // packed reduce of 13 per-wave partials: rows 0/1/2 of pbuf = S0/C/S
      float v = pbuf[lane];
      v = scan16(v);
      float S0 = bcast_lane(v, 15);
      float C  = bcast_lane(v, 31);
      float S  = bcast_lane(v, 47);
      float base = fmaf(0.002f, T0loc, 0.01f * S0);
      if (lane < 50) {
        float da = base - 0.01f * fmaf(cdA, C, sdA * S);   // col 2*lane
        float db = base - 0.01f * fmaf(cdB, C, sdB * S);   // col 2*lane+1
        *(float2*)(sun + 200 + 2*lane) = make_float2(fmaxf(da, 0.f), fmaxf(db, 0.f));
        *(float2*)(d7r + 2*lane)       = make_float2(da, db);
      }
    }
    bar_lgkm();
    p ^= 1;
  }

  // ---------- epilogue: output row 4999 + final carry ----------
  if (t < 300) {
    float v = (t < 200) ? su[p][t] : d7r[t-200];
    outb[(size_t)(SSTEPS-1) * 300 + t] = v;
    out[(size_t)64 * SSTEPS * 300 + (size_t)b * 300 + t] = v;
  }
}

extern "C" void kernel_launch(void* const* d_in, const int* in_sizes, int n_in,
                              void* d_out, int out_size, void* d_ws, size_t ws_size,
                              hipStream_t stream) {
  drosoph_rnn_kernel<<<64, 960, 0, stream>>>(
      (const float*)d_in[0],  // inputs
      (const float*)d_in[1],  // r0
      (const float*)d_in[2],  // W_HD_HD
      (const float*)d_in[3],  // W_HD_AVplus
      (const float*)d_in[4],  // W_HD_AVminus
      (const float*)d_in[5],  // W_AVplus_HD
      (const float*)d_in[6],  // W_AVminus_HD
      (const float*)d_in[7],  // W_Del7_HD
      (const float*)d_in[8],  // W_Del7_Del7
      (const float*)d_in[9],  // W_HD_Del7
      (float*)d_out);
}